// Round 6
// baseline (2604.936 us; speedup 1.0000x reference)
//
#include <hip/hip_runtime.h>

#define B 8
#define N 8192
#define S 2048
#define K 32
#define TPB 512           // all blocks: 8 waves
#define PPT (N / TPB)     // 16 contiguous points per FPS thread
#define HPT (PPT / 2)     // 8 packed float2 pairs per FPS thread
#define CHUNK_STEP 128    // FPS publish cadence
#define WPB 31            // worker blocks per batch
#define WVB (WPB * 8)     // 248 KNN waves per batch (stride)

typedef float v2f __attribute__((ext_vector_type(2)));

// Exact (no-FMA, left-to-right) squared distance to match numpy fp32:
// ((dx*dx + dy*dy) + dz*dz). FPS argmax is a chaotic recurrence; any ulp
// difference diverges the center sequence. Verified absmax==0 (R1-R13).
__device__ __forceinline__ float sqdist3(float ax, float ay, float az,
                                         float bx, float by, float bz) {
    float dx = ax - bx, dy = ay - by, dz = az - bz;
    return __fadd_rn(__fadd_rn(__fmul_rn(dx, dx), __fmul_rn(dy, dy)),
                     __fmul_rn(dz, dz));
}

// Dual-lane IEEE-RN fp32 via VOP3P inline asm (R11 showed the compiler
// scalarizes v2f arithmetic badly; asm pins the real instruction).
// v_pk_add_f32 / v_pk_mul_f32 = two independent f32 RN ops per instr.
__device__ __forceinline__ v2f pk_add(v2f a, v2f b) {
    v2f d;
    asm("v_pk_add_f32 %0, %1, %2" : "=v"(d) : "v"(a), "v"(b));
    return d;
}
__device__ __forceinline__ v2f pk_mul(v2f a, v2f b) {
    v2f d;
    asm("v_pk_mul_f32 %0, %1, %2" : "=v"(d) : "v"(a), "v"(b));
    return d;
}

template <int CTRL>
__device__ __forceinline__ float dpp_fmax(float v) {
    const int iv = __float_as_int(v);
    const int sh = __builtin_amdgcn_update_dpp(iv, iv, CTRL, 0xF, 0xF, false);
    return fmaxf(v, __int_as_float(sh));
}
__device__ __forceinline__ float wave_fmax_dpp(float v) {
    v = dpp_fmax<0x111>(v);  // row_shr:1
    v = dpp_fmax<0x112>(v);  // row_shr:2
    v = dpp_fmax<0x114>(v);  // row_shr:4
    v = dpp_fmax<0x118>(v);  // row_shr:8
    v = dpp_fmax<0x142>(v);  // row_bcast:15
    v = dpp_fmax<0x143>(v);  // row_bcast:31 -> lane 63 = wave max
    return __int_as_float(__builtin_amdgcn_readlane(__float_as_int(v), 63));
}

// ---------------------------------------------------------------------------
// R14: cut issue width of the update phase with REAL packed fp32 (inline asm).
//  - R13 post-mortem: lane-parallel reduce regressed (+330 us). The old
//    all-lanes-same-address scan is LDS BROADCAST (free, m136); my 770-cyc
//    LDS model was wrong. Serial chain rule re-confirmed: reverted to R10's
//    broadcast scan verbatim.
//  - Issue audit: ~340 dyn instrs/wave/step -> ~1360 cyc/SIMD issue floor of
//    the 2537-cyc step. Update (160) + md-copies (16) are the biggest block.
//  - NEW: x/y/z stored as float2 pairs; update uses v_pk_add_f32/v_pk_mul_f32
//    via inline asm (R11's failure was compiler LOWERING, not the ISA).
//    Subtraction = pk_add(x2, {-px,-px}): a+(-b) == a-b exactly in IEEE
//    (incl. +-0), negation is exact. Association ((dx^2+dy^2)+dz^2) and
//    RN rounding per component identical to sqdist3. md stays SCALAR
//    (no pk_min exists; subreg extracts of d2 halves are free); tree uses
//    fresh temps (kills the 16 md-copies). Update+tree: ~175 -> ~95
//    instrs/wave => ~-320 cyc/step predicted.
//  - Everything else = R10 verbatim (best: 2164 us).
// Tie-break invariants unchanged: FPS (max dist, min gid): thread = lowest i
// (descending overwrite; pair order j desc, .y then .x == i desc), wave =
// lowest lane (ballot ctz), block = lowest wid (strict > scan from w=0);
// KNN (d, idx) lexicographic == stable top_k. absmax must stay 0.
// ---------------------------------------------------------------------------
__global__ __launch_bounds__(TPB, 2) void fused_kernel(
    const float* __restrict__ xyz, float* __restrict__ out,
    float* __restrict__ centers, unsigned* __restrict__ progress) {
    const int blk = blockIdx.x;
    const int t = threadIdx.x;
    const int lane = t & 63;

    __shared__ float4 pub[2][8];       // per-wave {wmax,x,y,z}, dbuf

    if (blk < B) {
        // =================== FPS producer ===================
        const int b = blk;
        const float* xb = xyz + (size_t)b * N * 3;
        float* cb = centers + (size_t)b * S * 3;
        const int wid = t >> 6;

        v2f x2[HPT], y2[HPT], z2[HPT];
        float md[PPT];
        {
            float raw[3 * PPT];
            const float4* src = (const float4*)(xb + 3 * PPT * t);
#pragma unroll
            for (int i = 0; i < 3 * PPT / 4; ++i) {
                const float4 v = src[i];
                raw[4 * i + 0] = v.x; raw[4 * i + 1] = v.y;
                raw[4 * i + 2] = v.z; raw[4 * i + 3] = v.w;
            }
#pragma unroll
            for (int j = 0; j < HPT; ++j) {
                x2[j] = (v2f){raw[6 * j + 0], raw[6 * j + 3]};
                y2[j] = (v2f){raw[6 * j + 1], raw[6 * j + 4]};
                z2[j] = (v2f){raw[6 * j + 2], raw[6 * j + 5]};
                md[2 * j + 0] = INFINITY;
                md[2 * j + 1] = INFINITY;
            }
        }

        float px = xb[0], py = xb[1], pz = xb[2];   // step 0: point 0
        if (t == 0) { cb[0] = px; cb[1] = py; cb[2] = pz; }

        for (int s = 1; s < S; ++s) {
            // packed update (dual IEEE-RN fp32 per instr); scalar min;
            // copy-free tree over fresh temps.
            float t8[HPT];
            {
                const float nx = -px, ny = -py, nz = -pz;
                const v2f npx = {nx, nx}, npy = {ny, ny}, npz = {nz, nz};
#pragma unroll
                for (int j = 0; j < HPT; ++j) {
                    const v2f dx = pk_add(x2[j], npx);
                    const v2f dy = pk_add(y2[j], npy);
                    const v2f dz = pk_add(z2[j], npz);
                    const v2f d2 = pk_add(pk_add(pk_mul(dx, dx), pk_mul(dy, dy)),
                                          pk_mul(dz, dz));
                    const float a = fminf(md[2 * j + 0], d2.x);
                    const float c = fminf(md[2 * j + 1], d2.y);
                    md[2 * j + 0] = a;
                    md[2 * j + 1] = c;
                    t8[j] = fmaxf(a, c);
                }
            }
#pragma unroll
            for (int st = 1; st < HPT; st <<= 1)
#pragma unroll
                for (int j = 0; j < HPT; j += 2 * st)
                    t8[j] = fmaxf(t8[j], t8[j + st]);
            const float best = t8[0];

            // wave max (DPP) + first-lane tie-break via ballot
            const float wmax = wave_fmax_dpp(best);
            const unsigned long long mb = __ballot(best == wmax);
            const int ol = (int)__builtin_ctzll(mb);

            // owner: statically-indexed descending overwrite selects the
            // lowest-i match's coords (pure cndmask chain; subreg extracts
            // of the packed pairs are free, indices all compile-time).
            const int pb = s & 1;
            if (lane == ol) {
                float bx = x2[0].x, by = y2[0].x, bz = z2[0].x;
#pragma unroll
                for (int j = HPT - 1; j >= 0; --j) {
                    if (md[2 * j + 1] == wmax) { bx = x2[j].y; by = y2[j].y; bz = z2[j].y; }
                    if (md[2 * j + 0] == wmax) { bx = x2[j].x; by = y2[j].x; bz = z2[j].x; }
                }
                pub[pb][wid] = make_float4(wmax, bx, by, bz);
            }
            __syncthreads();               // the ONLY per-step barrier

            // serial scan of 8 wave winners: all lanes read the SAME address
            // -> LDS broadcast (free); strict > -> lowest wid on ties
            float4 v0 = pub[pb][0];
            float gmax = v0.x;
            px = v0.y; py = v0.z; pz = v0.w;
#pragma unroll
            for (int w = 1; w < 8; ++w) {
                const float4 u = pub[pb][w];
                const bool g = u.x > gmax;
                gmax = g ? u.x : gmax;
                px = g ? u.y : px;
                py = g ? u.z : py;
                pz = g ? u.w : pz;
            }

            // t0 streams the center straight to global (only t0 ever writes
            // centers; fire-and-forget, drained by the release below)
            if (t == 0) {
                float* cs = cb + 3 * s;
                cs[0] = px; cs[1] = py; cs[2] = pz;
            }

            // chunk publish: release store orders t0's prior center stores
            // (compiler emits vmcnt(0) drain + agent-scope writeback)
            if ((s & (CHUNK_STEP - 1)) == (CHUNK_STEP - 1)) {
                if (t == 0)
                    __hip_atomic_store(&progress[b], (unsigned)(s + 1),
                                       __ATOMIC_RELEASE, __HIP_MEMORY_SCOPE_AGENT);
            }
        }
    } else {
        // ======================= KNN workers ===============================
        const int w = blk - B;
        const int b = w & 7;               // same XCD as FPS block b (%8 rr)
        const int wchunk = w >> 3;         // 0..30
        const int waveid = wchunk * 8 + (t >> 6);   // 0..247 within batch
        const float* xb = xyz + (size_t)b * N * 3;

        unsigned seen = 0;                 // register-cached progress[b]
        for (int s = waveid; s < S; s += WVB) {
            // wait until progress[b] > s (all lanes load same line ->
            // broadcast; ACQUIRE invalidates L1 so center reads are fresh)
            while (seen <= (unsigned)s) {
                seen = __hip_atomic_load(&progress[b], __ATOMIC_ACQUIRE,
                                         __HIP_MEMORY_SCOPE_AGENT);
                if (seen <= (unsigned)s) __builtin_amdgcn_s_sleep(64);
            }

            const float* c = centers + (size_t)(b * S + s) * 3;
            const float cx = c[0], cy = c[1], cz = c[2];

            unsigned long long P = ~0ULL;   // lanes 0..31: sorted top-32 (asc)
            unsigned long long tau = ~0ULL;

            for (int i = 0; i < N / 64; ++i) {
                const int p = (i << 6) + lane;
                const float* q = xb + 3 * p;
                const float d = sqdist3(q[0], q[1], q[2], cx, cy, cz);
                const unsigned long long cand =
                    ((unsigned long long)__float_as_uint(d) << 32) | (unsigned)p;
                bool alive = cand < tau;
                unsigned long long mask = __ballot(alive);
                while (mask) {
                    const int src = __builtin_ctzll(mask);
                    const unsigned long long bc = __shfl(cand, src);
                    unsigned long long up = __shfl_up(P, 1);
                    if (lane == 0) up = bc;
                    const bool gt = P > bc;
                    const unsigned long long shifted = (up > bc) ? up : bc;
                    P = gt ? shifted : P;
                    tau = __shfl(P, 31);
                    if (lane == src) alive = false;
                    alive = alive && (cand < tau);
                    mask = __ballot(alive);
                }
            }

            if (lane < K) {
                const unsigned nidx = (unsigned)P;
                const float* q = xb + 3 * nidx;
                float* o = out + ((size_t)(b * S + s) * K + lane) * 3;
                o[0] = q[0] - cx;
                o[1] = q[1] - cy;
                o[2] = q[2] - cz;
            }
        }
    }
}

extern "C" void kernel_launch(void* const* d_in, const int* in_sizes, int n_in,
                              void* d_out, int out_size, void* d_ws, size_t ws_size,
                              hipStream_t stream) {
    const float* xyz = (const float*)d_in[0];
    float* out = (float*)d_out;                         // neighborhood [B,S,K,3]
    float* centers = out + (size_t)B * S * K * 3;       // centers [B,S,3]
    unsigned* progress = (unsigned*)d_ws;               // [B] centers-ready count

    // d_ws is poisoned 0xAA before every timed launch -> must zero progress
    hipMemsetAsync(d_ws, 0, B * sizeof(unsigned), stream);

    fused_kernel<<<B + WPB * B, TPB, 0, stream>>>(xyz, out, centers, progress);
}

// Round 7
// 2235.422 us; speedup vs baseline: 1.1653x; 1.1653x over previous
//
#include <hip/hip_runtime.h>

#define B 8
#define N 8192
#define S 2048
#define K 32
#define TPB 512           // all blocks: 8 waves
#define PPT (N / TPB)     // 16 contiguous points per FPS thread
#define CHUNK_STEP 128    // FPS publish cadence
#define WPB 31            // worker blocks per batch
#define WVB (WPB * 8)     // 248 KNN waves per batch (stride)

// Exact (no-FMA, left-to-right) squared distance to match numpy fp32:
// ((dx*dx + dy*dy) + dz*dz). FPS argmax is a chaotic recurrence; any ulp
// difference diverges the center sequence. Verified absmax==0 (R1-R14).
__device__ __forceinline__ float sqdist3(float ax, float ay, float az,
                                         float bx, float by, float bz) {
    float dx = ax - bx, dy = ay - by, dz = az - bz;
    return __fadd_rn(__fadd_rn(__fmul_rn(dx, dx), __fmul_rn(dy, dy)),
                     __fmul_rn(dz, dz));
}

template <int CTRL>
__device__ __forceinline__ float dpp_fmax(float v) {
    const int iv = __float_as_int(v);
    const int sh = __builtin_amdgcn_update_dpp(iv, iv, CTRL, 0xF, 0xF, false);
    return fmaxf(v, __int_as_float(sh));
}
__device__ __forceinline__ float wave_fmax_dpp(float v) {
    v = dpp_fmax<0x111>(v);  // row_shr:1
    v = dpp_fmax<0x112>(v);  // row_shr:2
    v = dpp_fmax<0x114>(v);  // row_shr:4
    v = dpp_fmax<0x118>(v);  // row_shr:8
    v = dpp_fmax<0x142>(v);  // row_bcast:15
    v = dpp_fmax<0x143>(v);  // row_bcast:31 -> lane 63 = wave max
    return __int_as_float(__builtin_amdgcn_readlane(__float_as_int(v), 63));
}

// ---------------------------------------------------------------------------
// R15: pin x/y/z in ArchVGPRs (kill load rematerialization).
//  - R14 post-mortem: inline-asm packed fp32 regressed (+440 us vs R10);
//    third failed issue-width attack. Reverted to R10 verbatim.
//  - The tell: R10's VGPR_Count=44 is IMPOSSIBLE for a resident working set
//    (x/y/z/md alone = 64 floats). No scratch traffic in FETCH_SIZE, and md
//    (mutated state) must be resident -> the compiler REMATERIALIZES x/y/z:
//    it re-issues the 12 global_load_dwordx4 per thread EVERY step instead
//    of keeping 48 regs live. Those re-loads hit L2 (96 KB/CU > 32 KB L1,
//    invisible in HBM FETCH) with ~200-cyc latency and only 2 waves/SIMD to
//    hide it -- sitting directly on the serial step chain. This explains
//    every failed VALU optimization: the binding term was VMEM all along.
//  - Fix: launder x[i]/y[i]/z[i] through empty asm("" : "+v") once after
//    init. Values become asm-defined -> rematerialization impossible ->
//    allocator must keep them live (budget 256 VGPR @ 2 waves/EU, need
//    ~110, no spill pressure). Zero added instructions, zero arithmetic
//    change.
//  - Everything else = R10 verbatim (best: 2164 us).
// Tie-break invariants unchanged: FPS (max dist, min gid): thread = lowest i
// (descending overwrite), wave = lowest lane (ballot ctz), block = lowest wid
// (strict > scan from w=0); KNN (d, idx) lexicographic == stable top_k.
// absmax must stay 0.
// ---------------------------------------------------------------------------
__global__ __launch_bounds__(TPB, 2) void fused_kernel(
    const float* __restrict__ xyz, float* __restrict__ out,
    float* __restrict__ centers, unsigned* __restrict__ progress) {
    const int blk = blockIdx.x;
    const int t = threadIdx.x;
    const int lane = t & 63;

    __shared__ float4 pub[2][8];       // per-wave {wmax,x,y,z}, dbuf

    if (blk < B) {
        // =================== FPS producer ===================
        const int b = blk;
        const float* xb = xyz + (size_t)b * N * 3;
        float* cb = centers + (size_t)b * S * 3;
        const int wid = t >> 6;

        float x[PPT], y[PPT], z[PPT], md[PPT];
        {
            float raw[3 * PPT];
            const float4* src = (const float4*)(xb + 3 * PPT * t);
#pragma unroll
            for (int i = 0; i < 3 * PPT / 4; ++i) {
                const float4 v = src[i];
                raw[4 * i + 0] = v.x; raw[4 * i + 1] = v.y;
                raw[4 * i + 2] = v.z; raw[4 * i + 3] = v.w;
            }
#pragma unroll
            for (int i = 0; i < PPT; ++i) {
                x[i] = raw[3 * i + 0];
                y[i] = raw[3 * i + 1];
                z[i] = raw[3 * i + 2];
                md[i] = INFINITY;
            }
            // Pin: make x/y/z asm-defined so the register allocator cannot
            // rematerialize the global loads inside the step loop. Empty
            // asm -> zero instructions, forces 48 live VGPRs.
#pragma unroll
            for (int i = 0; i < PPT; ++i)
                asm("" : "+v"(x[i]), "+v"(y[i]), "+v"(z[i]));
        }

        float px = xb[0], py = xb[1], pz = xb[2];   // step 0: point 0
        if (t == 0) { cb[0] = px; cb[1] = py; cb[2] = pz; }

        for (int s = 1; s < S; ++s) {
            // local update; tree max (values only, all static indices)
            float m[PPT];
#pragma unroll
            for (int i = 0; i < PPT; ++i) {
                const float d = sqdist3(x[i], y[i], z[i], px, py, pz);
                m[i] = fminf(md[i], d);
                md[i] = m[i];
            }
#pragma unroll
            for (int st = 1; st < PPT; st <<= 1)
#pragma unroll
                for (int i = 0; i < PPT; i += 2 * st)
                    m[i] = fmaxf(m[i], m[i + st]);
            const float best = m[0];

            // wave max (DPP) + first-lane tie-break via ballot
            const float wmax = wave_fmax_dpp(best);
            const unsigned long long mb = __ballot(best == wmax);
            const int ol = (int)__builtin_ctzll(mb);

            // owner: statically-indexed descending overwrite selects the
            // lowest-i match's coords (pure cndmask chain, no dynamic
            // register indexing anywhere) and publishes them inline.
            const int pb = s & 1;
            if (lane == ol) {
                float bx = x[0], by = y[0], bz = z[0];
#pragma unroll
                for (int i = PPT - 1; i >= 0; --i)
                    if (md[i] == wmax) { bx = x[i]; by = y[i]; bz = z[i]; }
                pub[pb][wid] = make_float4(wmax, bx, by, bz);
            }
            __syncthreads();               // the ONLY per-step barrier

            // serial scan of 8 wave winners: all lanes read the SAME address
            // -> LDS broadcast (free, m136); strict > -> lowest wid on ties
            float4 v0 = pub[pb][0];
            float gmax = v0.x;
            px = v0.y; py = v0.z; pz = v0.w;
#pragma unroll
            for (int w = 1; w < 8; ++w) {
                const float4 u = pub[pb][w];
                const bool g = u.x > gmax;
                gmax = g ? u.x : gmax;
                px = g ? u.y : px;
                py = g ? u.z : py;
                pz = g ? u.w : pz;
            }

            // t0 streams the center straight to global (only t0 ever writes
            // centers; fire-and-forget, drained by the release below)
            if (t == 0) {
                float* cs = cb + 3 * s;
                cs[0] = px; cs[1] = py; cs[2] = pz;
            }

            // chunk publish: release store orders t0's prior center stores
            // (compiler emits vmcnt(0) drain + agent-scope writeback)
            if ((s & (CHUNK_STEP - 1)) == (CHUNK_STEP - 1)) {
                if (t == 0)
                    __hip_atomic_store(&progress[b], (unsigned)(s + 1),
                                       __ATOMIC_RELEASE, __HIP_MEMORY_SCOPE_AGENT);
            }
        }
    } else {
        // ======================= KNN workers ===============================
        const int w = blk - B;
        const int b = w & 7;               // same XCD as FPS block b (%8 rr)
        const int wchunk = w >> 3;         // 0..30
        const int waveid = wchunk * 8 + (t >> 6);   // 0..247 within batch
        const float* xb = xyz + (size_t)b * N * 3;

        unsigned seen = 0;                 // register-cached progress[b]
        for (int s = waveid; s < S; s += WVB) {
            // wait until progress[b] > s (all lanes load same line ->
            // broadcast; ACQUIRE invalidates L1 so center reads are fresh)
            while (seen <= (unsigned)s) {
                seen = __hip_atomic_load(&progress[b], __ATOMIC_ACQUIRE,
                                         __HIP_MEMORY_SCOPE_AGENT);
                if (seen <= (unsigned)s) __builtin_amdgcn_s_sleep(64);
            }

            const float* c = centers + (size_t)(b * S + s) * 3;
            const float cx = c[0], cy = c[1], cz = c[2];

            unsigned long long P = ~0ULL;   // lanes 0..31: sorted top-32 (asc)
            unsigned long long tau = ~0ULL;

            for (int i = 0; i < N / 64; ++i) {
                const int p = (i << 6) + lane;
                const float* q = xb + 3 * p;
                const float d = sqdist3(q[0], q[1], q[2], cx, cy, cz);
                const unsigned long long cand =
                    ((unsigned long long)__float_as_uint(d) << 32) | (unsigned)p;
                bool alive = cand < tau;
                unsigned long long mask = __ballot(alive);
                while (mask) {
                    const int src = __builtin_ctzll(mask);
                    const unsigned long long bc = __shfl(cand, src);
                    unsigned long long up = __shfl_up(P, 1);
                    if (lane == 0) up = bc;
                    const bool gt = P > bc;
                    const unsigned long long shifted = (up > bc) ? up : bc;
                    P = gt ? shifted : P;
                    tau = __shfl(P, 31);
                    if (lane == src) alive = false;
                    alive = alive && (cand < tau);
                    mask = __ballot(alive);
                }
            }

            if (lane < K) {
                const unsigned nidx = (unsigned)P;
                const float* q = xb + 3 * nidx;
                float* o = out + ((size_t)(b * S + s) * K + lane) * 3;
                o[0] = q[0] - cx;
                o[1] = q[1] - cy;
                o[2] = q[2] - cz;
            }
        }
    }
}

extern "C" void kernel_launch(void* const* d_in, const int* in_sizes, int n_in,
                              void* d_out, int out_size, void* d_ws, size_t ws_size,
                              hipStream_t stream) {
    const float* xyz = (const float*)d_in[0];
    float* out = (float*)d_out;                         // neighborhood [B,S,K,3]
    float* centers = out + (size_t)B * S * K * 3;       // centers [B,S,3]
    unsigned* progress = (unsigned*)d_ws;               // [B] centers-ready count

    // d_ws is poisoned 0xAA before every timed launch -> must zero progress
    hipMemsetAsync(d_ws, 0, B * sizeof(unsigned), stream);

    fused_kernel<<<B + WPB * B, TPB, 0, stream>>>(xyz, out, centers, progress);
}

// Round 8
// 2168.690 us; speedup vs baseline: 1.2012x; 1.0308x over previous
//
#include <hip/hip_runtime.h>

#define B 8
#define N 8192
#define S 2048
#define K 32
#define TPB 512           // all blocks: 8 waves
#define PPT (N / TPB)     // 16 contiguous points per FPS thread
#define CHUNK_STEP 128    // FPS publish cadence
#define WPB 31            // worker blocks per batch
#define WVB (WPB * 8)     // 248 KNN waves per batch (stride)

// Exact (no-FMA, left-to-right) squared distance to match numpy fp32:
// ((dx*dx + dy*dy) + dz*dz). FPS argmax is a chaotic recurrence; any ulp
// difference diverges the center sequence. Verified absmax==0 (R1-R15).
__device__ __forceinline__ float sqdist3(float ax, float ay, float az,
                                         float bx, float by, float bz) {
    float dx = ax - bx, dy = ay - by, dz = az - bz;
    return __fadd_rn(__fadd_rn(__fmul_rn(dx, dx), __fmul_rn(dy, dy)),
                     __fmul_rn(dz, dz));
}

template <int CTRL>
__device__ __forceinline__ float dpp_fmax(float v) {
    const int iv = __float_as_int(v);
    const int sh = __builtin_amdgcn_update_dpp(iv, iv, CTRL, 0xF, 0xF, false);
    return fmaxf(v, __int_as_float(sh));
}
__device__ __forceinline__ float wave_fmax_dpp(float v) {
    v = dpp_fmax<0x111>(v);  // row_shr:1
    v = dpp_fmax<0x112>(v);  // row_shr:2
    v = dpp_fmax<0x114>(v);  // row_shr:4
    v = dpp_fmax<0x118>(v);  // row_shr:8
    v = dpp_fmax<0x142>(v);  // row_bcast:15
    v = dpp_fmax<0x143>(v);  // row_bcast:31 -> lane 63 = wave max
    return __int_as_float(__builtin_amdgcn_readlane(__float_as_int(v), 63));
}

// LDS-only block barrier: orders the pub ds_write/ds_read WITHOUT draining
// vmcnt. __syncthreads() emits "s_waitcnt vmcnt(0) expcnt(0) lgkmcnt(0);
// s_barrier" -- forcing wave 0 to wait for t0's per-step global center
// stores to retire (~200+ cyc) at EVERY barrier, stalling all 8 waves.
// The block barrier only needs LDS ordering; center-store visibility to
// workers is handled solely by the chunk-boundary RELEASE atomic (which
// drains wave 0's vmcnt there, amortized 1/128 steps). Pattern per the
// verified 8-phase template (guide §5, m194-m201): counted/selective
// waitcnt + raw s_barrier, sched_barrier(0) to pin scheduling.
__device__ __forceinline__ void barrier_lds_only() {
    __builtin_amdgcn_sched_barrier(0);
    asm volatile("s_waitcnt lgkmcnt(0)" ::: "memory");
    __builtin_amdgcn_s_barrier();
    __builtin_amdgcn_sched_barrier(0);
}

// ---------------------------------------------------------------------------
// R16: remove the per-step vmcnt(0) drain from the FPS barrier.
//  - R15 post-mortem: VGPR pin partially took (44->60 < the 64-reg floor)
//    and cost +70 us -> register residency/remat is NOT the binding term.
//    Dropped. Five non-wins on VALU/LDS/occupancy/regs leave one unmodeled
//    per-step cost: __syncthreads()' implicit vmcnt(0) drain of t0's 3
//    per-step global center stores (wave 0 stalls ~200+ cyc on L2 store
//    retire; all waves inherit via the barrier).
//  - Fix: barrier_lds_only() = s_waitcnt lgkmcnt(0) + raw s_barrier.
//    Global stores stay in flight across the barrier (<=~3 outstanding,
//    vmcnt cap 63, retire >> issue). Correctness: the barrier only needs
//    to order pub[] (LDS); centers are published to workers exclusively
//    via the RELEASE store (wave-0 vmcnt drain there, every 128 steps) +
//    worker ACQUIRE loads -- mechanism unchanged since R0, absmax==0.
//    Double-buffered pub + lgkmcnt(0)-before-barrier covers both the
//    owner's ds_write and all waves' scan ds_reads (reads of step s retire
//    before the step-s+1 barrier passes -> no WAR race on pb^1 reuse).
//  - Everything else = R10 verbatim (best: 2164 us).
// Tie-break invariants unchanged: FPS (max dist, min gid): thread = lowest i
// (descending overwrite), wave = lowest lane (ballot ctz), block = lowest wid
// (strict > scan from w=0); KNN (d, idx) lexicographic == stable top_k.
// absmax must stay 0.
// ---------------------------------------------------------------------------
__global__ __launch_bounds__(TPB, 2) void fused_kernel(
    const float* __restrict__ xyz, float* __restrict__ out,
    float* __restrict__ centers, unsigned* __restrict__ progress) {
    const int blk = blockIdx.x;
    const int t = threadIdx.x;
    const int lane = t & 63;

    __shared__ float4 pub[2][8];       // per-wave {wmax,x,y,z}, dbuf

    if (blk < B) {
        // =================== FPS producer ===================
        const int b = blk;
        const float* xb = xyz + (size_t)b * N * 3;
        float* cb = centers + (size_t)b * S * 3;
        const int wid = t >> 6;

        float x[PPT], y[PPT], z[PPT], md[PPT];
        {
            float raw[3 * PPT];
            const float4* src = (const float4*)(xb + 3 * PPT * t);
#pragma unroll
            for (int i = 0; i < 3 * PPT / 4; ++i) {
                const float4 v = src[i];
                raw[4 * i + 0] = v.x; raw[4 * i + 1] = v.y;
                raw[4 * i + 2] = v.z; raw[4 * i + 3] = v.w;
            }
#pragma unroll
            for (int i = 0; i < PPT; ++i) {
                x[i] = raw[3 * i + 0];
                y[i] = raw[3 * i + 1];
                z[i] = raw[3 * i + 2];
                md[i] = INFINITY;
            }
        }

        float px = xb[0], py = xb[1], pz = xb[2];   // step 0: point 0
        if (t == 0) { cb[0] = px; cb[1] = py; cb[2] = pz; }

        for (int s = 1; s < S; ++s) {
            // local update; tree max (values only, all static indices)
            float m[PPT];
#pragma unroll
            for (int i = 0; i < PPT; ++i) {
                const float d = sqdist3(x[i], y[i], z[i], px, py, pz);
                m[i] = fminf(md[i], d);
                md[i] = m[i];
            }
#pragma unroll
            for (int st = 1; st < PPT; st <<= 1)
#pragma unroll
                for (int i = 0; i < PPT; i += 2 * st)
                    m[i] = fmaxf(m[i], m[i + st]);
            const float best = m[0];

            // wave max (DPP) + first-lane tie-break via ballot
            const float wmax = wave_fmax_dpp(best);
            const unsigned long long mb = __ballot(best == wmax);
            const int ol = (int)__builtin_ctzll(mb);

            // owner: statically-indexed descending overwrite selects the
            // lowest-i match's coords (pure cndmask chain, no dynamic
            // register indexing anywhere) and publishes them inline.
            const int pb = s & 1;
            if (lane == ol) {
                float bx = x[0], by = y[0], bz = z[0];
#pragma unroll
                for (int i = PPT - 1; i >= 0; --i)
                    if (md[i] == wmax) { bx = x[i]; by = y[i]; bz = z[i]; }
                pub[pb][wid] = make_float4(wmax, bx, by, bz);
            }
            barrier_lds_only();            // LDS-ordered barrier, NO vmcnt drain

            // serial scan of 8 wave winners: all lanes read the SAME address
            // -> LDS broadcast (free, m136); strict > -> lowest wid on ties
            float4 v0 = pub[pb][0];
            float gmax = v0.x;
            px = v0.y; py = v0.z; pz = v0.w;
#pragma unroll
            for (int w = 1; w < 8; ++w) {
                const float4 u = pub[pb][w];
                const bool g = u.x > gmax;
                gmax = g ? u.x : gmax;
                px = g ? u.y : px;
                py = g ? u.z : py;
                pz = g ? u.w : pz;
            }

            // t0 streams the center straight to global (only t0 ever writes
            // centers; fire-and-forget, stays in flight across barriers,
            // drained only by the release below)
            if (t == 0) {
                float* cs = cb + 3 * s;
                cs[0] = px; cs[1] = py; cs[2] = pz;
            }

            // chunk publish: release store orders t0's prior center stores
            // (compiler emits vmcnt(0) drain for wave 0 only, 1/128 steps)
            if ((s & (CHUNK_STEP - 1)) == (CHUNK_STEP - 1)) {
                if (t == 0)
                    __hip_atomic_store(&progress[b], (unsigned)(s + 1),
                                       __ATOMIC_RELEASE, __HIP_MEMORY_SCOPE_AGENT);
            }
        }
    } else {
        // ======================= KNN workers ===============================
        const int w = blk - B;
        const int b = w & 7;               // same XCD as FPS block b (%8 rr)
        const int wchunk = w >> 3;         // 0..30
        const int waveid = wchunk * 8 + (t >> 6);   // 0..247 within batch
        const float* xb = xyz + (size_t)b * N * 3;

        unsigned seen = 0;                 // register-cached progress[b]
        for (int s = waveid; s < S; s += WVB) {
            // wait until progress[b] > s (all lanes load same line ->
            // broadcast; ACQUIRE invalidates L1 so center reads are fresh)
            while (seen <= (unsigned)s) {
                seen = __hip_atomic_load(&progress[b], __ATOMIC_ACQUIRE,
                                         __HIP_MEMORY_SCOPE_AGENT);
                if (seen <= (unsigned)s) __builtin_amdgcn_s_sleep(64);
            }

            const float* c = centers + (size_t)(b * S + s) * 3;
            const float cx = c[0], cy = c[1], cz = c[2];

            unsigned long long P = ~0ULL;   // lanes 0..31: sorted top-32 (asc)
            unsigned long long tau = ~0ULL;

            for (int i = 0; i < N / 64; ++i) {
                const int p = (i << 6) + lane;
                const float* q = xb + 3 * p;
                const float d = sqdist3(q[0], q[1], q[2], cx, cy, cz);
                const unsigned long long cand =
                    ((unsigned long long)__float_as_uint(d) << 32) | (unsigned)p;
                bool alive = cand < tau;
                unsigned long long mask = __ballot(alive);
                while (mask) {
                    const int src = __builtin_ctzll(mask);
                    const unsigned long long bc = __shfl(cand, src);
                    unsigned long long up = __shfl_up(P, 1);
                    if (lane == 0) up = bc;
                    const bool gt = P > bc;
                    const unsigned long long shifted = (up > bc) ? up : bc;
                    P = gt ? shifted : P;
                    tau = __shfl(P, 31);
                    if (lane == src) alive = false;
                    alive = alive && (cand < tau);
                    mask = __ballot(alive);
                }
            }

            if (lane < K) {
                const unsigned nidx = (unsigned)P;
                const float* q = xb + 3 * nidx;
                float* o = out + ((size_t)(b * S + s) * K + lane) * 3;
                o[0] = q[0] - cx;
                o[1] = q[1] - cy;
                o[2] = q[2] - cz;
            }
        }
    }
}

extern "C" void kernel_launch(void* const* d_in, const int* in_sizes, int n_in,
                              void* d_out, int out_size, void* d_ws, size_t ws_size,
                              hipStream_t stream) {
    const float* xyz = (const float*)d_in[0];
    float* out = (float*)d_out;                         // neighborhood [B,S,K,3]
    float* centers = out + (size_t)B * S * K * 3;       // centers [B,S,3]
    unsigned* progress = (unsigned*)d_ws;               // [B] centers-ready count

    // d_ws is poisoned 0xAA before every timed launch -> must zero progress
    hipMemsetAsync(d_ws, 0, B * sizeof(unsigned), stream);

    fused_kernel<<<B + WPB * B, TPB, 0, stream>>>(xyz, out, centers, progress);
}